// Round 1
// baseline (1298.174 us; speedup 1.0000x reference)
//
#include <hip/hip_runtime.h>
#include <math.h>

#define TT 16384
#define BB 4
#define CC 64
#define LL 30

typedef _Float16 f16;
typedef _Float16 f16x4 __attribute__((ext_vector_type(4)));
typedef _Float16 f16x8 __attribute__((ext_vector_type(8)));
typedef float f32x4 __attribute__((ext_vector_type(4)));

#define MFMA(a, b, c) __builtin_amdgcn_mfma_f32_16x16x32_f16(a, b, c, 0, 0, 0)

__device__ __forceinline__ float fsig(float x) { return 1.0f / (1.0f + __expf(-x)); }
__device__ __forceinline__ float ftanhf(float x) { return 1.0f - 2.0f / (__expf(2.0f * x) + 1.0f); }

// ---------------- weight packing to MFMA fragment layout (f16) ----------------
// conv: [L][3][64][128] -> [L][tap][kk2][nf8][lane64][e8]
// res:  [L-1][64][64]   -> [L-1][kk2][nf4][lane64][e8]
// skip: [L][64][64]     -> [L][kk2][nf4][lane64][e8]
__global__ void pack_weights(const float* __restrict__ conv_w, const float* __restrict__ res_w,
                             const float* __restrict__ skip_w,
                             f16* __restrict__ wcv, f16* __restrict__ wrs, f16* __restrict__ wsk) {
    const int total_c = LL * 3 * 2 * 8 * 64 * 8;    // 737280
    const int total_r = (LL - 1) * 2 * 4 * 64 * 8;  // 118784
    const int total_s = LL * 2 * 4 * 64 * 8;        // 122880
    const int total = total_c + total_r + total_s;
    for (int i = blockIdx.x * blockDim.x + threadIdx.x; i < total; i += gridDim.x * blockDim.x) {
        if (i < total_c) {
            int e = i & 7, lane = (i >> 3) & 63, nf = (i >> 9) & 7, kk2 = (i >> 12) & 1, lt = i >> 13;
            int k = kk2 * 32 + (lane >> 4) * 8 + e;
            int n = nf * 16 + (lane & 15);
            wcv[i] = (f16)conv_w[((size_t)lt * 64 + k) * 128 + n];
        } else if (i < total_c + total_r) {
            int j = i - total_c;
            int e = j & 7, lane = (j >> 3) & 63, nf = (j >> 9) & 3, kk2 = (j >> 11) & 1, l = j >> 12;
            int k = kk2 * 32 + (lane >> 4) * 8 + e;
            int n = nf * 16 + (lane & 15);
            wrs[j] = (f16)res_w[((size_t)l * 64 + k) * 64 + n];
        } else {
            int j = i - total_c - total_r;
            int e = j & 7, lane = (j >> 3) & 63, nf = (j >> 9) & 3, kk2 = (j >> 11) & 1, l = j >> 12;
            int k = kk2 * 32 + (lane >> 4) * 8 + e;
            int n = nf * 16 + (lane & 15);
            wsk[j] = (f16)skip_w[((size_t)l * 64 + k) * 64 + n];
        }
    }
}

// ---------------- x0 = relu(signal * in_w + in_b) ----------------
__global__ void init_x_kernel(const float* __restrict__ signal, const float* __restrict__ in_w,
                              const float* __restrict__ in_b, float* __restrict__ x0) {
    int i = blockIdx.x * 256 + threadIdx.x;  // < B*T*16
    int bt = i >> 4, c4 = i & 15;
    float s = signal[bt];
    float4 w = *(const float4*)(in_w + c4 * 4);
    float4 bb = *(const float4*)(in_b + c4 * 4);
    float4 o;
    o.x = fmaxf(s * w.x + bb.x, 0.f);
    o.y = fmaxf(s * w.y + bb.y, 0.f);
    o.z = fmaxf(s * w.z + bb.z, 0.f);
    o.w = fmaxf(s * w.w + bb.w, 0.f);
    *(float4*)(x0 + (size_t)bt * CC + c4 * 4) = o;
}

// ---------------- embedding table + swish MLP -> embed2[B][512] ----------------
__global__ void embed_mlp_kernel(const int* __restrict__ timestep,
                                 const float* __restrict__ pe0_w, const float* __restrict__ pe0_b,
                                 const float* __restrict__ pe1_w, const float* __restrict__ pe1_b,
                                 float* __restrict__ embed2) {
    __shared__ float emb[BB * 128];
    __shared__ float h1[BB * 512];
    const int tid = threadIdx.x;
    for (int i = tid; i < BB * 128; i += 256) {
        int b = i >> 7, j = i & 127;
        int jj = j & 63;
        // emulate fp32 pipeline: linspace (endpoint forced), pow->f32, f32 product, exact sin of that f32
        float logit = (jj == 63) ? 1.0f : (float)jj * (1.0f / 63.0f);
        double e10 = pow(10.0, (double)(4.0f * logit));
        float ef = (float)e10;
        float comp = ef * (float)timestep[b];
        float val = (j < 64) ? (float)sin((double)comp) : (float)cos((double)comp);
        emb[i] = val;
    }
    __syncthreads();
    const int u0 = tid, u1 = tid + 256;
    {
        float s[2][4] = {};
        for (int j = 0; j < 128; ++j) {
            float w0 = pe0_w[j * 512 + u0], w1 = pe0_w[j * 512 + u1];
#pragma unroll
            for (int b = 0; b < 4; ++b) {
                float ev = emb[b * 128 + j];
                s[0][b] += ev * w0;
                s[1][b] += ev * w1;
            }
        }
        float b0 = pe0_b[u0], b1 = pe0_b[u1];
#pragma unroll
        for (int b = 0; b < 4; ++b) {
            float x0 = s[0][b] + b0, x1 = s[1][b] + b1;
            h1[b * 512 + u0] = x0 * fsig(x0);
            h1[b * 512 + u1] = x1 * fsig(x1);
        }
    }
    __syncthreads();
    {
        float s[2][4] = {};
        for (int j = 0; j < 512; ++j) {
            float w0 = pe1_w[j * 512 + u0], w1 = pe1_w[j * 512 + u1];
#pragma unroll
            for (int b = 0; b < 4; ++b) {
                float hv = h1[b * 512 + j];
                s[0][b] += hv * w0;
                s[1][b] += hv * w1;
            }
        }
        float b0 = pe1_b[u0], b1 = pe1_b[u1];
#pragma unroll
        for (int b = 0; b < 4; ++b) {
            float x0 = s[0][b] + b0, x1 = s[1][b] + b1;
            embed2[b * 512 + u0] = x0 * fsig(x0);
            embed2[b * 512 + u1] = x1 * fsig(x1);
        }
    }
}

// ---------------- per-layer per-batch conv-tap embedding bias vectors ----------------
// evec[l][b][tap][128] = conv_w[l][tap]^T e[l][b]  (+ conv_b folded into tap 1)
__global__ void evec_kernel(const float* __restrict__ embed2, const float* __restrict__ blk_emb_w,
                            const float* __restrict__ blk_emb_b, const float* __restrict__ conv_w,
                            const float* __restrict__ conv_b, float* __restrict__ evec) {
    const int l = blockIdx.x, b = blockIdx.y;
    const int tid = threadIdx.x;
    __shared__ float em[512];
    __shared__ float e[64];
    __shared__ float red[256];
    for (int i = tid; i < 512; i += 256) em[i] = embed2[b * 512 + i];
    __syncthreads();
    {
        const int c = tid & 63, part = tid >> 6;
        float s = 0.f;
        for (int j = part * 128; j < part * 128 + 128; ++j)
            s += em[j] * blk_emb_w[((size_t)l * 512 + j) * 64 + c];
        red[tid] = s;
        __syncthreads();
        if (tid < 64)
            e[tid] = red[tid] + red[tid + 64] + red[tid + 128] + red[tid + 192] + blk_emb_b[l * 64 + tid];
        __syncthreads();
    }
    for (int o = tid; o < 384; o += 256) {
        int tap = o >> 7, n = o & 127;
        float s = (tap == 1) ? conv_b[l * 128 + n] : 0.f;
        for (int k = 0; k < 64; ++k)
            s += e[k] * conv_w[(((size_t)l * 3 + tap) * 64 + k) * 128 + n];
        evec[((size_t)(l * 4 + b) * 3 + tap) * 128 + n] = s;
    }
}

// ---------------- fused per-layer kernel ----------------
// block: 128 time rows x 1 batch; 4 waves.
__launch_bounds__(256, 2)
__global__ void layer_kernel(const float* __restrict__ x_in, float* __restrict__ x_out,
                             float* __restrict__ skip,
                             const f16* __restrict__ wcv,      // [6][8][64][8] this layer
                             const f16* __restrict__ wrs,      // [2][4][64][8] or null
                             const f16* __restrict__ wsk,      // [2][4][64][8]
                             const float* __restrict__ evec_l, // [B][3][128]
                             const float* __restrict__ res_b,  // [64] or null
                             const float* __restrict__ skip_b, // [64]
                             int d, int accum) {
    __shared__ f16 xs[3 * 128 * 72];
    const int tid = threadIdx.x;
    const int b = blockIdx.y;
    const int t0 = blockIdx.x * 128;
    const int lane = tid & 63;
    const int w = tid >> 6;
    const int wr = w >> 1, wc = w & 1;
    const int lrow = lane & 15, lk = lane >> 4;
    const float* xb = x_in + (size_t)b * TT * CC;

    // stage 3 dilated taps -> LDS f16 (rows padded to 72 halves = 144B, 16B aligned)
#pragma unroll
    for (int tap = 0; tap < 3; ++tap) {
        int toff = (tap - 1) * d;
#pragma unroll
        for (int j = 0; j < 8; ++j) {
            int idx = j * 256 + tid;
            int row = idx >> 4, c4 = idx & 15;
            int t = t0 + row + toff;
            float4 v = make_float4(0.f, 0.f, 0.f, 0.f);
            if (t >= 0 && t < TT) v = *(const float4*)(xb + (size_t)t * CC + c4 * 4);
            f16x4 h = {(f16)v.x, (f16)v.y, (f16)v.z, (f16)v.w};
            *(f16x4*)&xs[(tap * 128 + row) * 72 + c4 * 4] = h;
        }
    }
    __syncthreads();

    // conv GEMM: M128 x K192 x N128; wave (wr,wc): rows wr*64.., cols {2wc,2wc+1,2wc+4,2wc+5}*16
    f32x4 acc[4][4] = {};
#pragma unroll
    for (int ks = 0; ks < 6; ++ks) {
        const int tap = ks >> 1, kk = (ks & 1) * 32;
        const int ab = (tap * 128 + wr * 64 + lrow) * 72 + kk + lk * 8;
        f16x8 a[4];
#pragma unroll
        for (int mf = 0; mf < 4; ++mf) a[mf] = *(const f16x8*)&xs[ab + mf * 16 * 72];
#pragma unroll
        for (int nfi = 0; nfi < 4; ++nfi) {
            int nf = 2 * wc + (nfi & 1) + (nfi >> 1) * 4;
            f16x8 bf = *(const f16x8*)&wcv[((ks * 8 + nf) * 64 + lane) * 8];
#pragma unroll
            for (int mf = 0; mf < 4; ++mf) acc[mf][nfi] = MFMA(a[mf], bf, acc[mf][nfi]);
        }
    }
    __syncthreads();  // all LDS reads done before z overwrite

    // bias (embedding + conv_b via evec) + gating, z -> LDS (reuse tap0 region)
    const bool interior = (t0 >= d) && (t0 + 127 + d < TT);
    const float* evb = evec_l + b * 384;
#pragma unroll
    for (int nfi = 0; nfi < 2; ++nfi) {
        const int na = wc * 32 + nfi * 16 + lrow;  // tanh col
        const int nb = na + 64;                    // sigmoid col
        float ea = evb[128 + na], eb = evb[128 + nb];
        float ea0 = evb[na], eb0 = evb[nb];
        float ea2 = evb[256 + na], eb2 = evb[256 + nb];
        if (interior) { ea += ea0 + ea2; eb += eb0 + eb2; }
#pragma unroll
        for (int mf = 0; mf < 4; ++mf) {
#pragma unroll
            for (int r = 0; r < 4; ++r) {
                float ya = acc[mf][nfi][r] + ea;
                float yb = acc[mf][nfi + 2][r] + eb;
                if (!interior) {
                    int t = t0 + wr * 64 + mf * 16 + lk * 4 + r;
                    if (t >= d) { ya += ea0; yb += eb0; }
                    if (t + d < TT) { ya += ea2; yb += eb2; }
                }
                float zz = ftanhf(ya) * fsig(yb);
                xs[(wr * 64 + mf * 16 + lk * 4 + r) * 72 + na] = (f16)zz;
            }
        }
    }
    __syncthreads();

    // res & skip GEMMs: M128 x K64 x N64; wave w owns rows w*32..w*32+31
    const bool has_res = (wrs != nullptr);
    f32x4 ar[2][4] = {}, as2[2][4] = {};
#pragma unroll
    for (int kk = 0; kk < 2; ++kk) {
        const int ab2 = (w * 32 + lrow) * 72 + kk * 32 + lk * 8;
        f16x8 a0 = *(const f16x8*)&xs[ab2];
        f16x8 a1 = *(const f16x8*)&xs[ab2 + 16 * 72];
#pragma unroll
        for (int nf = 0; nf < 4; ++nf) {
            f16x8 bs = *(const f16x8*)&wsk[((kk * 4 + nf) * 64 + lane) * 8];
            as2[0][nf] = MFMA(a0, bs, as2[0][nf]);
            as2[1][nf] = MFMA(a1, bs, as2[1][nf]);
            if (has_res) {
                f16x8 br = *(const f16x8*)&wrs[((kk * 4 + nf) * 64 + lane) * 8];
                ar[0][nf] = MFMA(a0, br, ar[0][nf]);
                ar[1][nf] = MFMA(a1, br, ar[1][nf]);
            }
        }
    }

    float* skb = skip + (size_t)b * TT * CC;
    float* xob = has_res ? (x_out + (size_t)b * TT * CC) : nullptr;
#pragma unroll
    for (int nf = 0; nf < 4; ++nf) {
        const int col = nf * 16 + lrow;
        const float sb = skip_b[col];
        const float rb = has_res ? res_b[col] : 0.f;
#pragma unroll
        for (int mf = 0; mf < 2; ++mf) {
#pragma unroll
            for (int r = 0; r < 4; ++r) {
                int row = w * 32 + mf * 16 + lk * 4 + r;
                size_t gi = (size_t)(t0 + row) * CC + col;
                float sv = as2[mf][nf][r] + sb;
                if (accum) sv += skb[gi];
                skb[gi] = sv;
                if (has_res) {
                    float xv = xb[gi];
                    xob[gi] = (ar[mf][nf][r] + rb + xv) * 0.70710678118654752f;
                }
            }
        }
    }
}

// ---------------- output head: relu((skip/sqrt(L)) @ out0 + b0) @ out1 + b1 ----------------
__global__ void out_head(const float* __restrict__ skip, const float* __restrict__ out0_w,
                         const float* __restrict__ out0_b, const float* __restrict__ out1_w,
                         const float* __restrict__ out1_b, float* __restrict__ out) {
    const int lane = threadIdx.x & 63;
    const int wid = (blockIdx.x * blockDim.x + threadIdx.x) >> 6;  // 0..1023
    const float invL = 0.18257418583505537f;                       // 1/sqrt(30)
    const float b1 = out1_b[0];
    const float c0b = out0_b[lane];
    const float w1 = out1_w[lane];
    for (int r = wid * 64; r < wid * 64 + 64; ++r) {
        const float* srow = skip + (size_t)r * CC;
        float acc = 0.f;
#pragma unroll
        for (int k = 0; k < 64; ++k) acc += srow[k] * out0_w[k * 64 + lane];
        float ctx = fmaxf(acc * invL + c0b, 0.f);
        float p = ctx * w1;
#pragma unroll
        for (int off = 32; off; off >>= 1) p += __shfl_down(p, off);
        if (lane == 0) out[r] = p + b1;
    }
}

extern "C" void kernel_launch(void* const* d_in, const int* in_sizes, int n_in,
                              void* d_out, int out_size, void* d_ws, size_t ws_size,
                              hipStream_t stream) {
    const float* signal = (const float*)d_in[0];
    const int* timestep = (const int*)d_in[1];
    const float* in_w = (const float*)d_in[2];
    const float* in_b = (const float*)d_in[3];
    const float* pe0_w = (const float*)d_in[4];
    const float* pe0_b = (const float*)d_in[5];
    const float* pe1_w = (const float*)d_in[6];
    const float* pe1_b = (const float*)d_in[7];
    const float* blk_emb_w = (const float*)d_in[8];
    const float* blk_emb_b = (const float*)d_in[9];
    const float* blk_conv_w = (const float*)d_in[10];
    const float* blk_conv_b = (const float*)d_in[11];
    const float* blk_res_w = (const float*)d_in[12];
    const float* blk_res_b = (const float*)d_in[13];
    const float* blk_skip_w = (const float*)d_in[14];
    const float* blk_skip_b = (const float*)d_in[15];
    const float* out0_w = (const float*)d_in[16];
    const float* out0_b = (const float*)d_in[17];
    const float* out1_w = (const float*)d_in[18];
    const float* out1_b = (const float*)d_in[19];

    char* p = (char*)d_ws;
    const size_t xsz = (size_t)BB * TT * CC * sizeof(float);  // 16 MB
    float* xa = (float*)p; p += xsz;
    float* xb2 = (float*)p; p += xsz;
    float* skip = (float*)p; p += xsz;
    f16* wcv = (f16*)p; p += (size_t)737280 * 2;
    f16* wrs = (f16*)p; p += (size_t)118784 * 2;
    f16* wsk = (f16*)p; p += (size_t)122880 * 2;
    float* embed2 = (float*)p; p += 4 * 512 * sizeof(float);
    float* evec = (float*)p; p += (size_t)LL * 4 * 3 * 128 * sizeof(float);

    pack_weights<<<1024, 256, 0, stream>>>(blk_conv_w, blk_res_w, blk_skip_w, wcv, wrs, wsk);
    init_x_kernel<<<4096, 256, 0, stream>>>(signal, in_w, in_b, xa);
    embed_mlp_kernel<<<1, 256, 0, stream>>>(timestep, pe0_w, pe0_b, pe1_w, pe1_b, embed2);
    evec_kernel<<<dim3(LL, BB), 256, 0, stream>>>(embed2, blk_emb_w, blk_emb_b, blk_conv_w,
                                                  blk_conv_b, evec);

    float* cur = xa;
    float* nxt = xb2;
    for (int i = 0; i < LL; ++i) {
        int d = 1 << (i % 10);
        bool last = (i == LL - 1);
        layer_kernel<<<dim3(TT / 128, BB), 256, 0, stream>>>(
            cur, nxt, skip,
            wcv + (size_t)i * 24576,
            last ? nullptr : (wrs + (size_t)i * 4096),
            wsk + (size_t)i * 4096,
            evec + (size_t)i * 1536,
            last ? nullptr : (blk_res_b + i * 64),
            blk_skip_b + i * 64,
            d, i > 0 ? 1 : 0);
        if (!last) { float* t = cur; cur = nxt; nxt = t; }
    }

    out_head<<<256, 256, 0, stream>>>(skip, out0_w, out0_b, out1_w, out1_b, (float*)d_out);
}

// Round 2
// 838.900 us; speedup vs baseline: 1.5475x; 1.5475x over previous
//
#include <hip/hip_runtime.h>
#include <math.h>

#define TT 16384
#define BB 4
#define CC 64
#define LL 30

typedef _Float16 f16;
typedef _Float16 f16x4 __attribute__((ext_vector_type(4)));
typedef _Float16 f16x8 __attribute__((ext_vector_type(8)));
typedef float f32x4 __attribute__((ext_vector_type(4)));
typedef unsigned int u32;

#define MFMA(a, b, c) __builtin_amdgcn_mfma_f32_16x16x32_f16(a, b, c, 0, 0, 0)

__device__ __forceinline__ float fsig(float x) { return 1.0f / (1.0f + __expf(-x)); }
__device__ __forceinline__ float ftanhf(float x) { return 1.0f - 2.0f / (__expf(2.0f * x) + 1.0f); }

__device__ __forceinline__ void gl_lds16(const void* g, void* l) {
    __builtin_amdgcn_global_load_lds((const __attribute__((address_space(1))) u32*)g,
                                     (__attribute__((address_space(3))) u32*)l, 16, 0, 0);
}

// ---------------- weight packing: A-side (row = out-channel) MFMA fragments ----------------
// wcv[l][ks=tap*2+kk][mf8][lane][e8]; wrs/wsk[l][kk][mf4][lane][e8]
__global__ void pack_weights(const float* __restrict__ conv_w, const float* __restrict__ res_w,
                             const float* __restrict__ skip_w,
                             f16* __restrict__ wcv, f16* __restrict__ wrs, f16* __restrict__ wsk) {
    const int total_c = LL * 6 * 8 * 64 * 8;        // 737280
    const int total_r = (LL - 1) * 2 * 4 * 64 * 8;  // 118784
    const int total_s = LL * 2 * 4 * 64 * 8;        // 122880
    const int total = total_c + total_r + total_s;
    for (int i = blockIdx.x * blockDim.x + threadIdx.x; i < total; i += gridDim.x * blockDim.x) {
        if (i < total_c) {
            int e = i & 7, lane = (i >> 3) & 63, mf = (i >> 9) & 7, rest = i >> 12;
            int ks = rest % 6, l = rest / 6;
            int cin = (ks & 1) * 32 + (lane >> 4) * 8 + e;
            int tap = ks >> 1;
            int cout = mf * 16 + (lane & 15);
            wcv[i] = (f16)conv_w[(((size_t)l * 3 + tap) * 64 + cin) * 128 + cout];
        } else if (i < total_c + total_r) {
            int j = i - total_c;
            int e = j & 7, lane = (j >> 3) & 63, mf = (j >> 9) & 3, kk = (j >> 11) & 1, l = j >> 12;
            int cin = kk * 32 + (lane >> 4) * 8 + e;
            int cout = mf * 16 + (lane & 15);
            wrs[j] = (f16)res_w[((size_t)l * 64 + cin) * 64 + cout];
        } else {
            int j = i - total_c - total_r;
            int e = j & 7, lane = (j >> 3) & 63, mf = (j >> 9) & 3, kk = (j >> 11) & 1, l = j >> 12;
            int cin = kk * 32 + (lane >> 4) * 8 + e;
            int cout = mf * 16 + (lane & 15);
            wsk[j] = (f16)skip_w[((size_t)l * 64 + cin) * 64 + cout];
        }
    }
}

// ---------------- x0 = relu(signal * in_w + in_b) -> f16 ----------------
__global__ void init_x_kernel(const float* __restrict__ signal, const float* __restrict__ in_w,
                              const float* __restrict__ in_b, f16* __restrict__ x0) {
    int i = blockIdx.x * 256 + threadIdx.x;  // < B*T*8
    int bt = i >> 3, g = i & 7;
    float s = signal[bt];
    f32x4 w0 = *(const f32x4*)&in_w[g * 8];
    f32x4 w1 = *(const f32x4*)&in_w[g * 8 + 4];
    f32x4 b0 = *(const f32x4*)&in_b[g * 8];
    f32x4 b1 = *(const f32x4*)&in_b[g * 8 + 4];
    f16x8 o;
#pragma unroll
    for (int j = 0; j < 4; ++j) {
        o[j] = (f16)fmaxf(s * w0[j] + b0[j], 0.f);
        o[4 + j] = (f16)fmaxf(s * w1[j] + b1[j], 0.f);
    }
    *(f16x8*)&x0[(size_t)bt * CC + g * 8] = o;
}

// ---------------- embed stage 1: table + swish(pe0) -> h1[B][512] ----------------
__global__ void embed_stage1(const int* __restrict__ timestep, const float* __restrict__ pe0_w,
                             const float* __restrict__ pe0_b, float* __restrict__ h1) {
    __shared__ float emb[BB * 128];
    const int tid = threadIdx.x;
    for (int i = tid; i < BB * 128; i += 256) {
        int b = i >> 7, j = i & 127, jj = j & 63;
        float logit = (jj == 63) ? 1.0f : (float)jj * (1.0f / 63.0f);
        double e10 = pow(10.0, (double)(4.0f * logit));
        float comp = (float)e10 * (float)timestep[b];
        emb[i] = (j < 64) ? (float)sin((double)comp) : (float)cos((double)comp);
    }
    __syncthreads();
    const int col = blockIdx.x * 64 + (tid & 63), b = tid >> 6;
    float s = 0.f;
    for (int j = 0; j < 128; ++j) s += emb[b * 128 + j] * pe0_w[j * 512 + col];
    s += pe0_b[col];
    h1[b * 512 + col] = s * fsig(s);
}

// ---------------- embed stage 2: swish(pe1) -> embed2[B][512] ----------------
__global__ void embed_stage2(const float* __restrict__ h1, const float* __restrict__ pe1_w,
                             const float* __restrict__ pe1_b, float* __restrict__ embed2) {
    __shared__ float hs[BB * 512];
    const int tid = threadIdx.x;
    for (int i = tid; i < BB * 512; i += 256) hs[i] = h1[i];
    __syncthreads();
    const int col = blockIdx.x * 64 + (tid & 63), b = tid >> 6;
    float s = 0.f;
    for (int j = 0; j < 512; ++j) s += hs[b * 512 + j] * pe1_w[j * 512 + col];
    s += pe1_b[col];
    embed2[b * 512 + col] = s * fsig(s);
}

// ---------------- evec[l][b][tap][128] = conv_w[l][tap]^T e  (+conv_b at tap1) ----------------
__global__ void evec_kernel(const float* __restrict__ embed2, const float* __restrict__ blk_emb_w,
                            const float* __restrict__ blk_emb_b, const float* __restrict__ conv_w,
                            const float* __restrict__ conv_b, float* __restrict__ evec) {
    const int l = blockIdx.x, b = blockIdx.y;
    const int tid = threadIdx.x;
    __shared__ float em[512];
    __shared__ float e[64];
    __shared__ float red[256];
    for (int i = tid; i < 512; i += 256) em[i] = embed2[b * 512 + i];
    __syncthreads();
    {
        const int c = tid & 63, part = tid >> 6;
        float s = 0.f;
        for (int j = part * 128; j < part * 128 + 128; ++j)
            s += em[j] * blk_emb_w[((size_t)l * 512 + j) * 64 + c];
        red[tid] = s;
        __syncthreads();
        if (tid < 64)
            e[tid] = red[tid] + red[tid + 64] + red[tid + 128] + red[tid + 192] + blk_emb_b[l * 64 + tid];
        __syncthreads();
    }
    for (int o = tid; o < 384; o += 256) {
        int tap = o >> 7, n = o & 127;
        float s = (tap == 1) ? conv_b[l * 128 + n] : 0.f;
        for (int k = 0; k < 64; ++k)
            s += e[k] * conv_w[(((size_t)l * 3 + tap) * 64 + k) * 128 + n];
        evec[((size_t)(l * 4 + b) * 3 + tap) * 128 + n] = s;
    }
}

// ---------------- fused per-layer kernel: 128 time rows x 1 batch, 4 waves ----------------
__launch_bounds__(256, 2)
__global__ void layer_kernel(const f16* __restrict__ xin, f16* __restrict__ xout,
                             float* __restrict__ skip,
                             const f16* __restrict__ wcv,      // [6][8][64][8]
                             const f16* __restrict__ wrs,      // [2][4][64][8] or null
                             const f16* __restrict__ wsk,      // [2][4][64][8]
                             const float* __restrict__ evec_l, // [B][3][128]
                             const float* __restrict__ res_b, const float* __restrict__ skip_b,
                             const f16* __restrict__ zpage, int d, int accum) {
    __shared__ f16 xs[3 * 128 * 64];  // 48 KB, granule-XOR-swizzled: LDS[row][g] = X[row][g^(row&7)]
    __shared__ f16 zs[128 * 64];      // 16 KB, same swizzle
    const int tid = threadIdx.x, lane = tid & 63, w = tid >> 6;
    const int wr = w >> 1, wc = w & 1, lrow = lane & 15, lk = lane >> 4;
    const int b = blockIdx.y, t0 = blockIdx.x * 128;
    const f16* xb = xin + (size_t)b * TT * CC;

    // ---- stage 3 dilated taps via global_load_lds(16B), pre-swizzled source ----
#pragma unroll
    for (int j = 0; j < 12; ++j) {
        int chunk = j * 4 + w;          // 0..47, wave-uniform
        int gid = chunk * 64 + lane;    // granule id
        int tap = gid >> 10, row = (gid >> 3) & 127, g = gid & 7;
        int t = t0 + row + (tap - 1) * d;
        const f16* src = ((unsigned)t < TT) ? (xb + (size_t)t * CC + ((g ^ (row & 7)) << 3)) : zpage;
        gl_lds16(src, (void*)((char*)xs + chunk * 1024));
    }
    __syncthreads();

    // ---- conv GEMM: D[m=cout 128][n=time 128], K=192 ----
    f32x4 acc[4][4] = {};  // [mfi][nfi]
#pragma unroll
    for (int ks = 0; ks < 6; ++ks) {
        const int tap = ks >> 1, kk = ks & 1;
        f16x8 bx[4];
#pragma unroll
        for (int nfi = 0; nfi < 4; ++nfi) {
            int trow = wr * 64 + nfi * 16 + lrow;
            int g = kk * 4 + lk;
            bx[nfi] = *(const f16x8*)&xs[(tap * 128 + trow) * 64 + ((g ^ (trow & 7)) << 3)];
        }
#pragma unroll
        for (int mfi = 0; mfi < 4; ++mfi) {
            int mf = 2 * wc + (mfi & 1) + (mfi >> 1) * 4;
            f16x8 aw = *(const f16x8*)&wcv[((ks * 8 + mf) * 64 + lane) * 8];
#pragma unroll
            for (int nfi = 0; nfi < 4; ++nfi) acc[mfi][nfi] = MFMA(aw, bx[nfi], acc[mfi][nfi]);
        }
    }

    // ---- bias + gating, z -> zs (f16x4 writes, swizzled) ----
    const float* evb = evec_l + b * 384;
#pragma unroll
    for (int mfi = 0; mfi < 2; ++mfi) {
        const int ca = wc * 32 + mfi * 16 + lk * 4;  // tanh cout base; +64 = sigmoid
        f32x4 e0a = *(const f32x4*)&evb[ca],       e1a = *(const f32x4*)&evb[128 + ca],
              e2a = *(const f32x4*)&evb[256 + ca];
        f32x4 e0b = *(const f32x4*)&evb[64 + ca],  e1b = *(const f32x4*)&evb[192 + ca],
              e2b = *(const f32x4*)&evb[320 + ca];
        const int g = ca >> 3;
#pragma unroll
        for (int nfi = 0; nfi < 4; ++nfi) {
            int trow = wr * 64 + nfi * 16 + lrow;
            int t = t0 + trow;
            float m0 = (t >= d) ? 1.f : 0.f;
            float m2 = (t + d < TT) ? 1.f : 0.f;
            f32x4 ya = acc[mfi][nfi], yb = acc[mfi + 2][nfi];
            f16x4 zo;
#pragma unroll
            for (int r = 0; r < 4; ++r) {
                float ea = e1a[r] + m0 * e0a[r] + m2 * e2a[r];
                float eb = e1b[r] + m0 * e0b[r] + m2 * e2b[r];
                zo[r] = (f16)(ftanhf(ya[r] + ea) * fsig(yb[r] + eb));
            }
            *(f16x4*)&zs[trow * 64 + ((g ^ (trow & 7)) << 3) + (ca & 7)] = zo;
        }
    }
    __syncthreads();

    // ---- res & skip GEMMs: D[m=cout 64][n=time 128], K=64 ----
    const bool has_res = (wrs != nullptr);
    f32x4 accS[4][2] = {}, accR[4][2] = {};
#pragma unroll
    for (int kk = 0; kk < 2; ++kk) {
        f16x8 bz[2];
#pragma unroll
        for (int n2 = 0; n2 < 2; ++n2) {
            int trow = (w * 2 + n2) * 16 + lrow;
            int g = kk * 4 + lk;
            bz[n2] = *(const f16x8*)&zs[trow * 64 + ((g ^ (trow & 7)) << 3)];
        }
#pragma unroll
        for (int mf = 0; mf < 4; ++mf) {
            f16x8 as_ = *(const f16x8*)&wsk[((kk * 4 + mf) * 64 + lane) * 8];
#pragma unroll
            for (int n2 = 0; n2 < 2; ++n2) accS[mf][n2] = MFMA(as_, bz[n2], accS[mf][n2]);
            if (has_res) {
                f16x8 ar_ = *(const f16x8*)&wrs[((kk * 4 + mf) * 64 + lane) * 8];
#pragma unroll
                for (int n2 = 0; n2 < 2; ++n2) accR[mf][n2] = MFMA(ar_, bz[n2], accR[mf][n2]);
            }
        }
    }

    // ---- epilogue: float4 skip RMW, f16x4 x out (residual addend from LDS tap1) ----
    float* skb = skip + (size_t)b * TT * CC;
    f16* xob = has_res ? (xout + (size_t)b * TT * CC) : nullptr;
#pragma unroll
    for (int mf = 0; mf < 4; ++mf) {
        const int cout = mf * 16 + lk * 4;
        f32x4 sb4 = *(const f32x4*)&skip_b[cout];
        f32x4 rb4 = has_res ? *(const f32x4*)&res_b[cout] : f32x4{0.f, 0.f, 0.f, 0.f};
        const int gx = cout >> 3;
#pragma unroll
        for (int n2 = 0; n2 < 2; ++n2) {
            int trow = (w * 2 + n2) * 16 + lrow;
            size_t gi = (size_t)(t0 + trow) * CC + cout;
            f32x4 sv = accS[mf][n2] + sb4;
            if (accum) sv += *(const f32x4*)&skb[gi];
            *(f32x4*)&skb[gi] = sv;
            if (has_res) {
                f16x4 xv = *(const f16x4*)&xs[(128 + trow) * 64 + ((gx ^ (trow & 7)) << 3) + (cout & 7)];
                f16x4 xo;
#pragma unroll
                for (int r = 0; r < 4; ++r)
                    xo[r] = (f16)((accR[mf][n2][r] + rb4[r] + (float)xv[r]) * 0.70710678118654752f);
                *(f16x4*)&xob[gi] = xo;
            }
        }
    }
}

// ---------------- output head ----------------
__global__ void out_head(const float* __restrict__ skip, const float* __restrict__ out0_w,
                         const float* __restrict__ out0_b, const float* __restrict__ out1_w,
                         const float* __restrict__ out1_b, float* __restrict__ out) {
    const int lane = threadIdx.x & 63;
    const int wid = (blockIdx.x * blockDim.x + threadIdx.x) >> 6;  // 0..1023
    const float invL = 0.18257418583505537f;                       // 1/sqrt(30)
    const float b1 = out1_b[0];
    const float c0b = out0_b[lane];
    const float w1 = out1_w[lane];
    for (int r = wid * 64; r < wid * 64 + 64; ++r) {
        const float* srow = skip + (size_t)r * CC;
        float acc = 0.f;
#pragma unroll
        for (int k = 0; k < 64; ++k) acc += srow[k] * out0_w[k * 64 + lane];
        float ctx = fmaxf(acc * invL + c0b, 0.f);
        float p = ctx * w1;
#pragma unroll
        for (int off = 32; off; off >>= 1) p += __shfl_down(p, off);
        if (lane == 0) out[r] = p + b1;
    }
}

extern "C" void kernel_launch(void* const* d_in, const int* in_sizes, int n_in,
                              void* d_out, int out_size, void* d_ws, size_t ws_size,
                              hipStream_t stream) {
    const float* signal = (const float*)d_in[0];
    const int* timestep = (const int*)d_in[1];
    const float* in_w = (const float*)d_in[2];
    const float* in_b = (const float*)d_in[3];
    const float* pe0_w = (const float*)d_in[4];
    const float* pe0_b = (const float*)d_in[5];
    const float* pe1_w = (const float*)d_in[6];
    const float* pe1_b = (const float*)d_in[7];
    const float* blk_emb_w = (const float*)d_in[8];
    const float* blk_emb_b = (const float*)d_in[9];
    const float* blk_conv_w = (const float*)d_in[10];
    const float* blk_conv_b = (const float*)d_in[11];
    const float* blk_res_w = (const float*)d_in[12];
    const float* blk_res_b = (const float*)d_in[13];
    const float* blk_skip_w = (const float*)d_in[14];
    const float* blk_skip_b = (const float*)d_in[15];
    const float* out0_w = (const float*)d_in[16];
    const float* out0_b = (const float*)d_in[17];
    const float* out1_w = (const float*)d_in[18];
    const float* out1_b = (const float*)d_in[19];

    char* p = (char*)d_ws;
    const size_t xhsz = (size_t)BB * TT * CC * sizeof(f16);  // 8 MB
    f16* xa = (f16*)p; p += xhsz;
    f16* xb2 = (f16*)p; p += xhsz;
    float* skip = (float*)p; p += (size_t)BB * TT * CC * sizeof(float);  // 16 MB
    f16* wcv = (f16*)p; p += (size_t)737280 * 2;
    f16* wrs = (f16*)p; p += (size_t)118784 * 2;
    f16* wsk = (f16*)p; p += (size_t)122880 * 2;
    float* h1 = (float*)p; p += 4 * 512 * sizeof(float);
    float* embed2 = (float*)p; p += 4 * 512 * sizeof(float);
    float* evec = (float*)p; p += (size_t)LL * 4 * 3 * 128 * sizeof(float);
    f16* zpage = (f16*)p; p += 256;

    hipMemsetAsync(zpage, 0, 256, stream);
    pack_weights<<<1024, 256, 0, stream>>>(blk_conv_w, blk_res_w, blk_skip_w, wcv, wrs, wsk);
    init_x_kernel<<<2048, 256, 0, stream>>>(signal, in_w, in_b, xa);
    embed_stage1<<<8, 256, 0, stream>>>(timestep, pe0_w, pe0_b, h1);
    embed_stage2<<<8, 256, 0, stream>>>(h1, pe1_w, pe1_b, embed2);
    evec_kernel<<<dim3(LL, BB), 256, 0, stream>>>(embed2, blk_emb_w, blk_emb_b, blk_conv_w,
                                                  blk_conv_b, evec);

    f16* cur = xa;
    f16* nxt = xb2;
    for (int i = 0; i < LL; ++i) {
        int d = 1 << (i % 10);
        bool last = (i == LL - 1);
        layer_kernel<<<dim3(TT / 128, BB), 256, 0, stream>>>(
            cur, nxt, skip,
            wcv + (size_t)i * 24576,
            last ? nullptr : (wrs + (size_t)i * 4096),
            wsk + (size_t)i * 4096,
            evec + (size_t)i * 1536,
            last ? nullptr : (blk_res_b + i * 64),
            blk_skip_b + i * 64,
            zpage, d, i > 0 ? 1 : 0);
        if (!last) { f16* t = cur; cur = nxt; nxt = t; }
    }

    out_head<<<256, 256, 0, stream>>>(skip, out0_w, out0_b, out1_w, out1_b, (float*)d_out);
}